// Round 15
// baseline (335.303 us; speedup 1.0000x reference)
//
#include <hip/hip_runtime.h>
#include <math.h>

// ---------------- problem constants ----------------
#define NHEADS 16
#define DHEAD  64
#define NDIM   1024
#define NB     8
#define NSEQ   512
#define NROWS  4096
#define NHB    128
#define NTOTD  33554432.0    // 16*8*512*512

typedef __bf16 bf16x8 __attribute__((ext_vector_type(8)));
typedef __bf16 bf16x4 __attribute__((ext_vector_type(4)));
typedef float  f32x4  __attribute__((ext_vector_type(4)));

#define MFMA(a,b,c) __builtin_amdgcn_mfma_f32_16x16x32_bf16(a,b,c,0,0,0)

// Q/K fragment-order index: [hb][n>>4][d>>3][n&15][d&7]
static __device__ __forceinline__ size_t qk_off(int hbq, int n, int d){
  return ((size_t)hbq*32 + (n>>4))*1024 + (size_t)(d>>3)*128 + (size_t)(n&15)*8 + (d&7);
}

// ---------------- workspace byte offsets ----------------
#define O_DSUMH  0           // [16][5] doubles
#define O_DSUME  1024        // [4] doubles
#define O_SCAL   2048
#define O_COEF   3072
#define O_W      4096
#define O_RQ1    131072      // f32 [65536] each
#define O_RQ2    393216
#define O_MQ     655360
#define O_QDMK   917504
#define O_RK1    1179648
#define O_RK2    1441792
#define O_KS2    1703936
#define O_MARG   1966080
#define O_RCS    2228224
#define O_RCOV   2490368
#define O_MK     2752512     // f32 [128][64]
#define O_QCOL   2785280     // f32 [128][64]
#define O_QHI    4194304     // bf16 fragment-order, 8 MB each
#define O_QLO    12582912
#define O_KHI    20971520
#define O_KLO    29360128
#define O_VTH    37748736    // bf16 fragment-order V [128][4][16][64][8]
#define O_VTL    46137344
#define O_LNST   54525952    // f32 [3][4096][2]
#define O_WTH    71303168    // bf16 [1024][1024] = 2 MB each
#define O_WTL    73400320
#define O_OUTH   75497472    // bf16 [4096][1024]
#define O_OUTL   83886080
#define O_WOTH   92274688
#define O_WOTL   94371840
// end = 96468992 (~92 MB)

static __device__ __forceinline__ float clamp98(float x){ return fminf(fmaxf(x,-0.98f),0.98f); }

// ---------------- LN row stats for q/k/v (mu, rstd) ----------------
__global__ __launch_bounds__(256) void ln_stats_kernel(const float* __restrict__ q,
    const float* __restrict__ k, const float* __restrict__ v, float* __restrict__ st){
  int row = blockIdx.x, t = threadIdx.x;
  const float* x = (blockIdx.y==0) ? q : (blockIdx.y==1 ? k : v);
  float4 vv = *(const float4*)(x + (size_t)row*1024 + t*4);
  float s  = vv.x+vv.y+vv.z+vv.w;
  float ss = vv.x*vv.x+vv.y*vv.y+vv.z*vv.z+vv.w*vv.w;
  for (int off=32; off; off>>=1){ s += __shfl_down(s,off); ss += __shfl_down(ss,off); }
  __shared__ float sh[8];
  if ((t&63)==0){ sh[t>>6]=s; sh[4+(t>>6)]=ss; }
  __syncthreads();
  if (t==0){
    float S=sh[0]+sh[1]+sh[2]+sh[3], SS=sh[4]+sh[5]+sh[6]+sh[7];
    float mu = S*(1.0f/1024.0f);
    st[blockIdx.y*8192 + row*2]   = mu;
    st[blockIdx.y*8192 + row*2+1] = 1.0f/sqrtf(SS*(1.0f/1024.0f) - mu*mu + 1e-5f);
  }
}

// ---------------- transpose + split a [1024][1024] f32 weight (row-major out) ----------------
__global__ __launch_bounds__(256) void transpose_split_kernel(const float* __restrict__ wsrc,
    __bf16* __restrict__ th, __bf16* __restrict__ tl){
  __shared__ float tile[64][65];
  int k0 = blockIdx.x*64, n0 = blockIdx.y*64;
  int t = threadIdx.x;
  int c = t&63, r4 = t>>6;
  #pragma unroll
  for (int i=0;i<16;i++){
    int kr = r4 + i*4;
    tile[kr][c] = wsrc[(size_t)(k0+kr)*1024 + n0 + c];
  }
  __syncthreads();
  #pragma unroll
  for (int i=0;i<16;i++){
    int nr = r4 + i*4;
    float v = tile[c][nr];
    __bf16 hv = (__bf16)v;
    size_t o = (size_t)(n0+nr)*1024 + k0 + c;
    th[o] = hv; tl[o] = (__bf16)(v - (float)hv);
  }
}

// ---------------- merged proj GEMM (LN fused), z: 0=Q 1=K (frag-order) 2=V (frag-order V) ----------------
// Pad 68 (52.2KB LDS) -> 3 blocks/CU.
__global__ __launch_bounds__(256) void proj_gemm_kernel(
  const float* __restrict__ q, const float* __restrict__ k, const float* __restrict__ v,
  const float* __restrict__ lnst0,
  const float* __restrict__ gv, const float* __restrict__ bv,
  const __bf16* __restrict__ Bth, const __bf16* __restrict__ Btl,
  __bf16* __restrict__ qhi, __bf16* __restrict__ qlo,
  __bf16* __restrict__ khi, __bf16* __restrict__ klo,
  __bf16* __restrict__ vth, __bf16* __restrict__ vtl)
{
  __shared__ __bf16 Ash[128][68];
  __shared__ __bf16 Asl[128][68];
  __shared__ __bf16 Bsh[64][68];
  __shared__ __bf16 Bsl[64][68];
  int z = blockIdx.z;
  const float* X = (z==0)? q : (z==1? k : v);
  const float* lnst = lnst0 + z*8192;
  __bf16* oh = (z==0)? qhi : (z==1? khi : vth);
  __bf16* ol = (z==0)? qlo : (z==1? klo : vtl);
  int t = threadIdx.x, w = t>>6, lane = t&63, lr = lane&15, lq = lane>>4;
  int vid = blockIdx.y*16 + blockIdx.x;
  int cX = vid&7, r2 = vid>>3;
  int ytile = cX*4 + (r2>>4);
  int xtile = r2&15;
  int rbase = ytile*128;
  int cbase = xtile*64;
  int wr = w>>1, wc = w&1;
  int srow = t>>3;
  int scol = (t&7)*8;
  f32x4 acc[4][2] = {};
  for (int kt=0; kt<16; kt++){
    int k0 = kt*64;
    bf16x8 va[4], vA[4], vb[2], vB[2];
    float4 g0 = *(const float4*)(gv + k0 + scol);
    float4 g1 = *(const float4*)(gv + k0 + scol + 4);
    float4 b0 = *(const float4*)(bv + k0 + scol);
    float4 b1 = *(const float4*)(bv + k0 + scol + 4);
    #pragma unroll
    for (int r=0;r<4;r++){
      int row = rbase + r*32 + srow;
      size_t gi = (size_t)row*1024 + k0 + scol;
      float4 x0 = *(const float4*)(X + gi);
      float4 x1 = *(const float4*)(X + gi + 4);
      float mu = lnst[row*2], rs = lnst[row*2+1];
      float o[8];
      o[0]=(x0.x-mu)*rs*g0.x+b0.x; o[1]=(x0.y-mu)*rs*g0.y+b0.y;
      o[2]=(x0.z-mu)*rs*g0.z+b0.z; o[3]=(x0.w-mu)*rs*g0.w+b0.w;
      o[4]=(x1.x-mu)*rs*g1.x+b1.x; o[5]=(x1.y-mu)*rs*g1.y+b1.y;
      o[6]=(x1.z-mu)*rs*g1.z+b1.z; o[7]=(x1.w-mu)*rs*g1.w+b1.w;
      bf16x8 hv, lv;
      #pragma unroll
      for (int e=0;e<8;e++){
        __bf16 hb_ = (__bf16)o[e];
        hv[e] = hb_; lv[e] = (__bf16)(o[e]-(float)hb_);
      }
      va[r]=hv; vA[r]=lv;
    }
    #pragma unroll
    for (int r=0;r<2;r++){
      size_t gi = (size_t)(cbase + r*32 + srow)*1024 + k0 + scol;
      vb[r] = *(const bf16x8*)(Bth + gi);
      vB[r] = *(const bf16x8*)(Btl + gi);
    }
    #pragma unroll
    for (int r=0;r<4;r++){
      *(bf16x8*)&Ash[r*32+srow][scol] = va[r];
      *(bf16x8*)&Asl[r*32+srow][scol] = vA[r];
    }
    #pragma unroll
    for (int r=0;r<2;r++){
      *(bf16x8*)&Bsh[r*32+srow][scol] = vb[r];
      *(bf16x8*)&Bsl[r*32+srow][scol] = vB[r];
    }
    __syncthreads();
    #pragma unroll
    for (int kc=0; kc<2; kc++){
      int ko = kc*32 + lq*8;
      bf16x8 ah[4], al[4], bh[2], bl[2];
      #pragma unroll
      for (int i=0;i<4;i++){
        ah[i] = *(const bf16x8*)&Ash[wr*64 + i*16 + lr][ko];
        al[i] = *(const bf16x8*)&Asl[wr*64 + i*16 + lr][ko];
      }
      #pragma unroll
      for (int j=0;j<2;j++){
        bh[j] = *(const bf16x8*)&Bsh[wc*32 + j*16 + lr][ko];
        bl[j] = *(const bf16x8*)&Bsl[wc*32 + j*16 + lr][ko];
      }
      #pragma unroll
      for (int i=0;i<4;i++)
        #pragma unroll
        for (int j=0;j<2;j++){
          acc[i][j] = MFMA(al[i], bh[j], acc[i][j]);
          acc[i][j] = MFMA(ah[i], bl[j], acc[i][j]);
          acc[i][j] = MFMA(ah[i], bh[j], acc[i][j]);
        }
    }
    __syncthreads();
  }
  // epilogue
  #pragma unroll
  for (int i=0;i<4;i++)
    #pragma unroll
    for (int j=0;j<2;j++)
      #pragma unroll
      for (int r=0;r<4;r++){
        int row = rbase + wr*64 + i*16 + lq*4 + r;
        int col = cbase + wc*32 + j*16 + lr;
        float val = acc[i][j][r];
        __bf16 hv = (__bf16)val;
        __bf16 lv = (__bf16)(val - (float)hv);
        int n = row & 511, b2 = row >> 9;
        int hh = col >> 6, d = col & 63;
        int hbq = hh*8 + b2;
        size_t o;
        if (z<2){
          o = qk_off(hbq, n, d);
        } else {
          o = (((size_t)hbq*4 + (d>>4))*16 + (n>>5))*512
            + (size_t)((((n>>3)&3)*16) + (d&15))*8 + (n&7);
        }
        oh[o] = hv; ol[o] = lv;
      }
}

// ---------------- final GEMM: out = outpre @ w_out^T + bias (LDS-staged, pad 68) ----------------
__global__ __launch_bounds__(256) void final_gemm_kernel(
  const __bf16* __restrict__ Ah, const __bf16* __restrict__ Al,
  const __bf16* __restrict__ Bth, const __bf16* __restrict__ Btl,
  const float* __restrict__ bias, float* __restrict__ of)
{
  __shared__ __bf16 Ash[128][68];
  __shared__ __bf16 Asl[128][68];
  __shared__ __bf16 Bsh[64][68];
  __shared__ __bf16 Bsl[64][68];
  int t = threadIdx.x, w = t>>6, lane = t&63, lr = lane&15, lq = lane>>4;
  int vid = blockIdx.y*16 + blockIdx.x;
  int cX = vid&7, r2 = vid>>3;
  int ytile = cX*4 + (r2>>4);
  int xtile = r2&15;
  int rbase = ytile*128;
  int cbase = xtile*64;
  int wr = w>>1, wc = w&1;
  int srow = t>>3;
  int scol = (t&7)*8;
  f32x4 acc[4][2] = {};
  for (int kt=0; kt<16; kt++){
    int k0 = kt*64;
    bf16x8 va[4], vA[4], vb[2], vB[2];
    #pragma unroll
    for (int r=0;r<4;r++){
      size_t gi = (size_t)(rbase + r*32 + srow)*1024 + k0 + scol;
      va[r] = *(const bf16x8*)(Ah + gi);
      vA[r] = *(const bf16x8*)(Al + gi);
    }
    #pragma unroll
    for (int r=0;r<2;r++){
      size_t gi = (size_t)(cbase + r*32 + srow)*1024 + k0 + scol;
      vb[r] = *(const bf16x8*)(Bth + gi);
      vB[r] = *(const bf16x8*)(Btl + gi);
    }
    #pragma unroll
    for (int r=0;r<4;r++){
      *(bf16x8*)&Ash[r*32+srow][scol] = va[r];
      *(bf16x8*)&Asl[r*32+srow][scol] = vA[r];
    }
    #pragma unroll
    for (int r=0;r<2;r++){
      *(bf16x8*)&Bsh[r*32+srow][scol] = vb[r];
      *(bf16x8*)&Bsl[r*32+srow][scol] = vB[r];
    }
    __syncthreads();
    #pragma unroll
    for (int kc=0; kc<2; kc++){
      int ko = kc*32 + lq*8;
      bf16x8 ah[4], al[4], bh[2], bl[2];
      #pragma unroll
      for (int i=0;i<4;i++){
        ah[i] = *(const bf16x8*)&Ash[wr*64 + i*16 + lr][ko];
        al[i] = *(const bf16x8*)&Asl[wr*64 + i*16 + lr][ko];
      }
      #pragma unroll
      for (int j=0;j<2;j++){
        bh[j] = *(const bf16x8*)&Bsh[wc*32 + j*16 + lr][ko];
        bl[j] = *(const bf16x8*)&Bsl[wc*32 + j*16 + lr][ko];
      }
      #pragma unroll
      for (int i=0;i<4;i++)
        #pragma unroll
        for (int j=0;j<2;j++){
          acc[i][j] = MFMA(al[i], bh[j], acc[i][j]);
          acc[i][j] = MFMA(ah[i], bl[j], acc[i][j]);
          acc[i][j] = MFMA(ah[i], bh[j], acc[i][j]);
        }
    }
    __syncthreads();
  }
  #pragma unroll
  for (int i=0;i<4;i++)
    #pragma unroll
    for (int j=0;j<2;j++)
      #pragma unroll
      for (int r=0;r<4;r++){
        int row = rbase + wr*64 + i*16 + lq*4 + r;
        int col = cbase + wc*32 + j*16 + lr;
        of[(size_t)row*1024 + col] = acc[i][j][r] + bias[col];
      }
}

// ---------------- per-(h,b) key stats (fragment-order input) ----------------
__global__ void kstats_kernel(const __bf16* __restrict__ kh, const __bf16* __restrict__ kl,
    float* __restrict__ mk, float* __restrict__ rk1, float* __restrict__ rk2, float* __restrict__ ks2){
  int hb = blockIdx.x;
  size_t base = (size_t)hb*32768;
  int t = threadIdx.x;
  __shared__ float csA[32][64];
  __shared__ float mks_lds[64];
  __shared__ float mksum_sh;
  int c2 = t&7, mg = t>>3;
  float fs[8] = {};
  for (int m=mg; m<512; m+=32){
    size_t off = base + (size_t)(m>>4)*1024 + c2*128 + (size_t)(m&15)*8;
    bf16x8 h = *(const bf16x8*)(kh+off);
    bf16x8 l = *(const bf16x8*)(kl+off);
    #pragma unroll
    for (int e=0;e<8;e++) fs[e] += (float)h[e]+(float)l[e];
  }
  #pragma unroll
  for (int e=0;e<8;e++) csA[mg][c2*8+e] = fs[e];
  __syncthreads();
  if (t<64){
    float s=0;
    #pragma unroll
    for (int g=0;g<32;g++) s += csA[g][t];
    float vv = s*(1.0f/512.0f);
    mk[hb*64+t] = vv;
    mks_lds[t] = vv;
  }
  __syncthreads();
  if (t==0){
    float s=0;
    for (int i=0;i<64;i++) s += mks_lds[i];
    mksum_sh = s;
  }
  __syncthreads();
  float mks = mksum_sh;
  int l8 = t&7, rg = t>>3;
  for (int m=rg; m<512; m+=32){
    size_t off = base + (size_t)(m>>4)*1024 + l8*128 + (size_t)(m&15)*8;
    bf16x8 h = *(const bf16x8*)(kh+off);
    bf16x8 l = *(const bf16x8*)(kl+off);
    float s=0, ss=0;
    #pragma unroll
    for (int e=0;e<8;e++){ float vv=(float)h[e]+(float)l[e]; s+=vv; ss+=vv*vv; }
    for (int o2=4;o2;o2>>=1){ s+=__shfl_xor(s,o2); ss+=__shfl_xor(ss,o2); }
    if (l8==0){
      float nk = sqrtf(ss);
      rk1[hb*512+m] = 1.0f/(nk+1e-8f);
      rk2[hb*512+m] = 1.0f/fmaxf(nk,1e-6f);
      ks2[hb*512+m] = s - mks;
    }
  }
}

// ---------------- per-(h,b) query stats (fragment-order input) ----------------
__global__ void qstats_kernel(const __bf16* __restrict__ qh, const __bf16* __restrict__ ql,
    const float* __restrict__ mk, float* __restrict__ rq1, float* __restrict__ rq2,
    float* __restrict__ mq, float* __restrict__ qdotmk, float* __restrict__ qcol){
  int hb = blockIdx.x;
  size_t base = (size_t)hb*32768;
  int t = threadIdx.x;
  __shared__ float csA[32][64];
  __shared__ float mks_lds[64];
  int c2 = t&7, mg = t>>3;
  if (t<64) mks_lds[t] = mk[hb*64+t];
  float fs[8] = {};
  for (int m=mg; m<512; m+=32){
    size_t off = base + (size_t)(m>>4)*1024 + c2*128 + (size_t)(m&15)*8;
    bf16x8 h = *(const bf16x8*)(qh+off);
    bf16x8 l = *(const bf16x8*)(ql+off);
    #pragma unroll
    for (int e=0;e<8;e++) fs[e] += (float)h[e]+(float)l[e];
  }
  #pragma unroll
  for (int e=0;e<8;e++) csA[mg][c2*8+e] = fs[e];
  __syncthreads();
  if (t<64){
    float s=0;
    #pragma unroll
    for (int g=0;g<32;g++) s += csA[g][t];
    qcol[hb*64+t] = s;
  }
  int l8 = t&7, rg = t>>3;
  float mkv[8];
  #pragma unroll
  for (int e=0;e<8;e++) mkv[e] = mks_lds[l8*8+e];
  for (int n=rg; n<512; n+=32){
    size_t off = base + (size_t)(n>>4)*1024 + l8*128 + (size_t)(n&15)*8;
    bf16x8 h = *(const bf16x8*)(qh+off);
    bf16x8 l = *(const bf16x8*)(ql+off);
    float s=0, ss=0, qd=0;
    #pragma unroll
    for (int e=0;e<8;e++){
      float vv=(float)h[e]+(float)l[e];
      s+=vv; ss+=vv*vv; qd+=vv*mkv[e];
    }
    for (int o2=4;o2;o2>>=1){ s+=__shfl_xor(s,o2); ss+=__shfl_xor(ss,o2); qd+=__shfl_xor(qd,o2); }
    if (l8==0){
      float nq = sqrtf(ss);
      rq1[hb*512+n] = 1.0f/(nq+1e-8f);
      rq2[hb*512+n] = 1.0f/fmaxf(nq,1e-6f);
      mq[hb*512+n]  = s*(1.0f/64.0f);
      qdotmk[hb*512+n] = qd;
    }
  }
}

// ---------------- per-head weight MLP ----------------
__global__ void mlp_kernel(const float* __restrict__ qcol, const float* __restrict__ mk,
   const float* __restrict__ w1, const float* __restrict__ b1, const float* __restrict__ lng,
   const float* __restrict__ lnb, const float* __restrict__ w2, const float* __restrict__ b2,
   const float* __restrict__ w3, const float* __restrict__ b3, const float* __restrict__ wtemp,
   float* __restrict__ W){
  int h = blockIdx.x;
  int j = threadIdx.x;
  __shared__ float qk[128], h1[64], h2[32];
  float sq=0, sk=0;
  #pragma unroll
  for (int b=0;b<8;b++){
    sq += qcol[(h*8+b)*64 + j];
    sk += mk[(h*8+b)*64 + j];
  }
  qk[j]    = sq*(1.0f/4096.0f);
  qk[64+j] = sk*(1.0f/8.0f);
  __syncthreads();
  float a = b1[j];
  for (int i=0;i<128;i++) a += qk[i]*w1[i*64+j];
  float s=a, ss=a*a;
  for (int off=32; off; off>>=1){ s += __shfl_xor(s,off); ss += __shfl_xor(ss,off); }
  float mu = s*(1.0f/64.0f), var = ss*(1.0f/64.0f)-mu*mu;
  float v = (a-mu)/sqrtf(var+1e-5f)*lng[j] + lnb[j];
  h1[j] = fmaxf(v, 0.0f);
  __syncthreads();
  if (j<32){
    float a2 = b2[j];
    for (int i=0;i<64;i++) a2 += h1[i]*w2[i*32+j];
    h2[j] = fmaxf(a2,0.0f);
  }
  __syncthreads();
  if (j==0){
    float l[3];
    for (int kq=0;kq<3;kq++){ float a3=b3[kq]; for(int i=0;i<32;i++) a3 += h2[i]*w3[i*3+kq]; l[kq]=a3; }
    float m = fmaxf(l[0],fmaxf(l[1],l[2]));
    float e0=expf(l[0]-m), e1=expf(l[1]-m), e2=expf(l[2]-m);
    float si = 1.0f/(e0+e1+e2);
    float temp = fminf(fmaxf(wtemp[0], 0.1f), 5.0f);
    float t0=e0*si/temp, t1=e1*si/temp, t2=e2*si/temp;
    float m2 = fmaxf(t0,fmaxf(t1,t2));
    float f0=expf(t0-m2), f1=expf(t1-m2), f2=expf(t2-m2);
    float s2i = 1.0f/(f0+f1+f2);
    float wv[3] = {f0*s2i, f1*s2i, f2*s2i};
    float wsum=0.0f;
    for (int kq=0;kq<3;kq++){ wv[kq]=fminf(fmaxf(wv[kq],0.08f),0.75f); wsum+=wv[kq]; }
    for (int kq=0;kq<3;kq++) W[h*3+kq] = wv[kq]/wsum;
  }
}

// ---------------- S1 v3 (MFMA): 64-row blocks for occupancy, wave tile 16x512 ----------------
__global__ __launch_bounds__(256) void s1_mfma_kernel(
  const __bf16* __restrict__ qhp, const __bf16* __restrict__ qlp,
  const __bf16* __restrict__ khp, const __bf16* __restrict__ klp,
  const float* __restrict__ rq1, const float* __restrict__ rq2,
  const float* __restrict__ mq, const float* __restrict__ qdmk,
  const float* __restrict__ rk1, const float* __restrict__ rk2,
  const float* __restrict__ ks2,
  double* __restrict__ dsumH, float* __restrict__ margin,
  float* __restrict__ rcs, float* __restrict__ rcov)
{
  int vid = blockIdx.y*8 + blockIdx.x;
  int cX = vid&7, r2 = vid>>3;       // r2: 0..127
  int hb = cX*16 + (r2>>3);
  int n0 = (r2&7)*64;
  size_t qb = (size_t)hb*32768;
  __shared__ float sm[512][3];
  __shared__ float sn[64][4];
  int t = threadIdx.x;
  for (int mm=t; mm<512; mm+=256){
    int m = hb*512 + mm;
    sm[mm][0]=rk1[m]; sm[mm][1]=rk2[m]; sm[mm][2]=ks2[m];
  }
  if (t<64){
    int n = hb*512 + n0 + t;
    sn[t][0]=rq1[n]; sn[t][1]=rq2[n]; sn[t][2]=mq[n]; sn[t][3]=qdmk[n];
  }
  __syncthreads();
  int w = t>>6, lane = t&63, lr = lane&15, lq = lane>>4;
  int nw = w*16;
  float lcs=0,lcs2=0,lcov=0,lcov2=0,lcscov=0;
  float mrow[4]={}, csr[4]={}, cvr[4]={};
  float nr1[4],nr2[4],nmq[4],nqd[4];
  #pragma unroll
  for (int r=0;r<4;r++){
    int nl = nw + lq*4 + r;
    nr1[r]=sn[nl][0]; nr2[r]=sn[nl][1]; nmq[r]=sn[nl][2]; nqd[r]=sn[nl][3];
  }
  for (int mc=0; mc<4; mc++){
    int m0 = mc*128;
    f32x4 acc[8] = {};
    #pragma unroll
    for (int kc=0; kc<2; kc++){
      size_t qoff = qb + (size_t)((n0+nw)>>4)*1024 + kc*512 + (size_t)lane*8;
      bf16x8 ah = *(const bf16x8*)(qhp + qoff);
      bf16x8 al = *(const bf16x8*)(qlp + qoff);
      #pragma unroll
      for (int j=0;j<8;j++){
        size_t off = qb + (size_t)((m0>>4)+j)*1024 + kc*512 + (size_t)lane*8;
        bf16x8 bh = *(const bf16x8*)(khp + off);
        bf16x8 bl = *(const bf16x8*)(klp + off);
        acc[j] = MFMA(ah, bh, acc[j]);
        acc[j] = MFMA(ah, bl, acc[j]);
        acc[j] = MFMA(al, bh, acc[j]);
      }
    }
    #pragma unroll
    for (int j=0;j<8;j++){
      int ml = m0 + j*16 + lr;
      float k1=sm[ml][0], k2=sm[ml][1], ksv=sm[ml][2];
      #pragma unroll
      for (int r=0;r<4;r++){
        float dv = acc[j][r];
        float cs = clamp98(dv*nr1[r]*k1);
        float c2 = clamp98(dv*nr2[r]*k2);
        float mg = fminf(fmaxf(0.01f-c2,0.0f),5.0f);
        float cv = dv - nqd[r] - nmq[r]*ksv;
        lcs+=cs; lcs2+=cs*cs; lcov+=cv; lcov2+=cv*cv; lcscov+=cs*cv;
        mrow[r]+=mg; csr[r]+=cs; cvr[r]+=cv;
      }
    }
  }
  for (int off=1; off<16; off<<=1)
    #pragma unroll
    for (int r=0;r<4;r++){
      mrow[r]+=__shfl_xor(mrow[r],off);
      csr[r] +=__shfl_xor(csr[r],off);
      cvr[r]+=__shfl_xor(cvr[r],off);
    }
  if (lr==0){
    #pragma unroll
    for (int r=0;r<4;r++){
      int n = hb*512 + n0 + nw + lq*4 + r;
      margin[n] = mrow[r]*(1.0f/512.0f);
      rcs[n]    = csr[r];
      rcov[n]   = cvr[r];
    }
  }
  for (int off=32; off; off>>=1){
    lcs+=__shfl_xor(lcs,off); lcs2+=__shfl_xor(lcs2,off);
    lcov+=__shfl_xor(lcov,off); lcov2+=__shfl_xor(lcov2,off);
    lcscov+=__shfl_xor(lcscov,off);
  }
  __shared__ double red[4][5];
  if (lane==0){ red[w][0]=lcs; red[w][1]=lcs2; red[w][2]=lcov; red[w][3]=lcov2; red[w][4]=lcscov; }
  __syncthreads();
  if (t==0){
    int h = hb>>3;
    for (int c=0;c<5;c++)
      atomicAdd(&dsumH[h*5+c], red[0][c]+red[1][c]+red[2][c]+red[3][c]);
  }
}

// ---------------- var_c moments ----------------
__global__ void margfin_kernel(const float* __restrict__ margin, double* __restrict__ dsumE){
  double s=0, ss=0;
  for (int k2=0;k2<4;k2++){
    int idx = blockIdx.x*1024 + k2*256 + threadIdx.x;
    float v = margin[idx];
    s += v; ss += (double)v*v;
  }
  for (int off=32; off; off>>=1){ s+=__shfl_down(s,off); ss+=__shfl_down(ss,off); }
  __shared__ double sh[8];
  int t = threadIdx.x;
  if ((t&63)==0){ sh[t>>6]=s; sh[4+(t>>6)]=ss; }
  __syncthreads();
  if (t==0){
    atomicAdd(dsumE+0, sh[0]+sh[1]+sh[2]+sh[3]);
    atomicAdd(dsumE+1, sh[4]+sh[5]+sh[6]+sh[7]);
  }
}

// ---------------- fold stats into per-head coefficients ----------------
__global__ void scalars1_kernel(const double* __restrict__ dsumH, double* __restrict__ dsumE,
                                const float* __restrict__ W, float* __restrict__ coef){
  double Scs=0,Scs2=0,Scov=0,Scov2=0;
  for (int h=0;h<16;h++){
    Scs += dsumH[h*5+0]; Scs2 += dsumH[h*5+1];
    Scov += dsumH[h*5+2]; Scov2 += dsumH[h*5+3];
  }
  double N = NTOTD;
  double cn = sqrt(fmax((Scs2-Scs*Scs/N)/(N-1.0),0.0)) + 1e-6;
  double ch = fmin(cn, 1.0);
  const double covscale = 1.0/8.000001;
  double sc_ = Scov*covscale, sc2_ = Scov2*covscale*covscale;
  double health = sqrt(fmax((sc2_-sc_*sc_/N)/(N-1.0),0.0));
  double base = 0.001/512.0;
  double reg = health<1e-5 ? base*5.0 : (health<1e-3 ? base*2.0 : base);
  double covn = reg*health + 1e-6;
  double covh = fmin(covn*10.0, 1.0);
  double vs = dsumE[0]*512.0, vs2 = dsumE[1]*512.0;
  double varn = sqrt(fmax((vs2 - vs*vs/N)/(N-1.0),0.0)) + 1e-6;
  double varh = fmin(varn*10.0, 1.0);
  double sdf=0, sdf2=0;
  for (int h=0;h<16;h++){
    double cC  = (double)W[h*3+0]*ch/cn;
    double cCv = (double)W[h*3+1]*reg*covscale*0.4*covh/covn;
    double cVr = (double)W[h*3+2]*0.4*varh/varn;
    coef[h*3+0] = (float)cC;
    coef[h*3+1] = (float)cCv;
    coef[h*3+2] = (float)cVr;
    sdf  += cC*dsumH[h*5+0] + cCv*dsumH[h*5+2];
    sdf2 += cC*cC*dsumH[h*5+1] + cCv*cCv*dsumH[h*5+3] + 2.0*cC*cCv*dsumH[h*5+4];
  }
  dsumE[2] = sdf;
  dsumE[3] = sdf2;
}

// ---------------- row-level fold of df moments ----------------
__global__ void rowfold_kernel(const float* __restrict__ margin, const float* __restrict__ rcs,
                               const float* __restrict__ rcov, const float* __restrict__ coef,
                               double* __restrict__ dsumE){
  int idx = blockIdx.x*256 + threadIdx.x;
  int h = idx >> 12;
  float cC = coef[h*3+0], cCv = coef[h*3+1], cVr = coef[h*3+2];
  float vc = cVr * margin[idx];
  double s0 = 512.0*(double)vc;
  double s1 = 2.0*(double)vc*((double)cC*(double)rcs[idx] + (double)cCv*(double)rcov[idx])
            + 512.0*(double)vc*(double)vc;
  for (int off=32; off; off>>=1){ s0+=__shfl_down(s0,off); s1+=__shfl_down(s1,off); }
  __shared__ double sh[8];
  int t = threadIdx.x;
  if ((t&63)==0){ sh[t>>6]=s0; sh[4+(t>>6)]=s1; }
  __syncthreads();
  if (t==0){
    atomicAdd(dsumE+2, sh[0]+sh[1]+sh[2]+sh[3]);
    atomicAdd(dsumE+3, sh[4]+sh[5]+sh[6]+sh[7]);
  }
}

// ---------------- finalize adaptive temperature ----------------
__global__ void scalars2_kernel(const double* __restrict__ dsumE, float* __restrict__ scal){
  double N = NTOTD;
  double div = sqrt(fmax((dsumE[3]-dsumE[2]*dsumE[2]/N)/(N-1.0),0.0));
  double at = div<1e-5 ? 0.05 : (div<1e-3 ? 0.2 : 0.5+div);
  at = fmin(fmax(at,0.05),2.0);
  scal[0] = (float)(1.0/at);
}

// ---------------- S3 (MFMA): 32-row blocks + XCD swizzle + frag-order Q/K/V ----------------
#define PSTRIDE 536
__global__ __launch_bounds__(512) void s3_mfma_kernel(
  const __bf16* __restrict__ qhp, const __bf16* __restrict__ qlp,
  const __bf16* __restrict__ khp, const __bf16* __restrict__ klp,
  const __bf16* __restrict__ vth, const __bf16* __restrict__ vtl,
  const float* __restrict__ rq1, const float* __restrict__ mq,
  const float* __restrict__ qdmk, const float* __restrict__ rk1,
  const float* __restrict__ ks2, const float* __restrict__ margin,
  const float* __restrict__ coef, const float* __restrict__ scal,
  __bf16* __restrict__ outh, __bf16* __restrict__ outl)
{
  int vid = blockIdx.y*16 + blockIdx.x;
  int cX = vid&7, r2 = vid>>3;
  int hb = cX*16 + (r2>>4);
  int n0 = (r2&15)*32;
  int h = hb>>3, b = hb&7;
  size_t qb = (size_t)hb*32768;

  __shared__ unsigned short Plds[32][PSTRIDE];
  __shared__ float nst[32][4];
  __shared__ float mst[512][2];
  __shared__ float pmax[32][8];
  __shared__ float psum[32][8];

  int t = threadIdx.x, w = t>>6, lane = t&63, lr = lane&15, lq = lane>>4;
  if (t<32){
    int n = hb*512 + n0 + t;
    nst[t][0] = rq1[n]; nst[t][1] = mq[n]; nst[t][2] = qdmk[n];
    nst[t][3] = coef[h*3+2]*margin[n];
  }
  {
    int m = hb*512 + t;
    mst[t][0] = rk1[m]; mst[t][1] = ks2[m];
  }
  float cC = coef[h*3+0], cCv = coef[h*3+1];
  float invat = scal[0];
  __syncthreads();

  int ms0 = w*64;
  f32x4 acc[2][4] = {};
  #pragma unroll
  for (int kc=0; kc<2; kc++){
    bf16x8 qhf[2], qlf[2];
    #pragma unroll
    for (int i=0;i<2;i++){
      size_t off = qb + (size_t)((n0>>4)+i)*1024 + kc*512 + (size_t)lane*8;
      qhf[i] = *(const bf16x8*)(qhp + off);
      qlf[i] = *(const bf16x8*)(qlp + off);
    }
    #pragma unroll
    for (int j=0;j<4;j++){
      size_t off = qb + (size_t)((ms0>>4)+j)*1024 + kc*512 + (size_t)lane*8;
      bf16x8 khf = *(const bf16x8*)(khp + off);
      bf16x8 klf = *(const bf16x8*)(klp + off);
      #pragma unroll
      for (int i=0;i<2;i++){
        acc[i][j] = MFMA(qlf[i], khf, acc[i][j]);
        acc[i][j] = MFMA(qhf[i], klf, acc[i][j]);
        acc[i][j] = MFMA(qhf[i], khf, acc[i][j]);
      }
    }
  }
  float rmax[2][4];
  #pragma unroll
  for (int i=0;i<2;i++){
    float a0[4],a1[4],a2[4],a3[4];
    #pragma unroll
    for (int r=0;r<4;r++){
      int nl = i*16 + lq*4 + r;
      a0[r]=nst[nl][0]; a1[r]=nst[nl][1]; a2[r]=nst[nl][2]; a3[r]=nst[nl][3];
      rmax[i][r] = -1e30f;
    }
    #pragma unroll
    for (int j=0;j<4;j++){
      int m = ms0 + j*16 + lr;
      float k1 = mst[m][0], ksv = mst[m][1];
      #pragma unroll
      for (int r=0;r<4;r++){
        float dv = acc[i][j][r];
        float cs = clamp98(dv*a0[r]*k1);
        float covr = dv - a2[r] - a1[r]*ksv;
        float df = cC*cs + cCv*covr + a3[r];
        acc[i][j][r] = df;
        rmax[i][r] = fmaxf(rmax[i][r], df);
      }
    }
  }
  #pragma unroll
  for (int i=0;i<2;i++)
    #pragma unroll
    for (int r=0;r<4;r++)
      for (int off=1; off<16; off<<=1)
        rmax[i][r] = fmaxf(rmax[i][r], __shfl_xor(rmax[i][r], off));
  if (lr==0){
    #pragma unroll
    for (int i=0;i<2;i++)
      #pragma unroll
      for (int r=0;r<4;r++)
        pmax[i*16+lq*4+r][w] = rmax[i][r];
  }
  __syncthreads();
  float rsum[2][4] = {};
  #pragma unroll
  for (int i=0;i<2;i++){
    float Mf[4];
    #pragma unroll
    for (int r=0;r<4;r++){
      int nl = i*16+lq*4+r;
      float m0_ = fmaxf(fmaxf(pmax[nl][0],pmax[nl][1]),fmaxf(pmax[nl][2],pmax[nl][3]));
      float m1_ = fmaxf(fmaxf(pmax[nl][4],pmax[nl][5]),fmaxf(pmax[nl][6],pmax[nl][7]));
      Mf[r] = fmaxf(m0_,m1_);
    }
    #pragma unroll
    for (int j=0;j<4;j++){
      int m = ms0 + j*16 + lr;
      #pragma unroll
      for (int r=0;r<4;r++){
        float p = __expf((acc[i][j][r]-Mf[r])*invat);
        rsum[i][r] += p;
        *(__bf16*)&Plds[i*16+lq*4+r][m] = (__bf16)p;
      }
    }
  }
  #pragma unroll
  for (int i=0;i<2;i++)
    #pragma unroll
    for (int r=0;r<4;r++)
      for (int off=1; off<16; off<<=1)
        rsum[i][r] += __shfl_xor(rsum[i][r], off);
  if (lr==0){
    #pragma unroll
    for (int i=0;i<2;i++)
      #pragma unroll
      for (int r=0;r<4;r++)
        psum[i*16+lq*4+r][w] = rsum[i][r];
  }
  __syncthreads();

  int rt = (w&1)*16;
  int dtg = w>>1;
  f32x4 acc2 = {};
  for (int kc=0; kc<16; kc++){
    bf16x8 pa = *(const bf16x8*)&Plds[rt+lr][kc*32 + lq*8];
    size_t vi = (((size_t)hb*4 + dtg)*16 + kc)*512 + (size_t)lane*8;
    bf16x8 vh = *(const bf16x8*)(vth + vi);
    bf16x8 vl = *(const bf16x8*)(vtl + vi);
    acc2 = MFMA(pa, vl, acc2);
    acc2 = MFMA(pa, vh, acc2);
  }
  float rsinv[4];
  #pragma unroll
  for (int r=0;r<4;r++){
    int nl = rt + lq*4 + r;
    float s0_ = psum[nl][0]+psum[nl][1]+psum[nl][2]+psum[nl][3];
    float s1_ = psum[nl][4]+psum[nl][5]+psum[nl][6]+psum[nl][7];
    rsinv[r] = 1.0f/(s0_+s1_);
  }
  #pragma unroll
  for (int r=0;r<4;r++){
    float o = acc2[r]*rsinv[r];
    int rowg = b*512 + n0 + rt + lq*4 + r;
    int colg = h*64 + dtg*16 + lr;
    size_t oi = (size_t)rowg*1024 + colg;
    __bf16 hv = (__bf16)o;
    outh[oi] = hv;
    outl[oi] = (__bf16)(o - (float)hv);
  }
}

// ---------------- launch ----------------
extern "C" void kernel_launch(void* const* d_in, const int* in_sizes, int n_in,
                              void* d_out, int out_size, void* d_ws, size_t ws_size,
                              hipStream_t stream) {
  (void)in_sizes; (void)n_in; (void)out_size; (void)ws_size;
  const float* q     = (const float*)d_in[0];
  const float* k     = (const float*)d_in[1];
  const float* v     = (const float*)d_in[2];
  const float* ln_g  = (const float*)d_in[3];
  const float* ln_b  = (const float*)d_in[4];
  const float* w_in  = (const float*)d_in[5];
  const float* wp_w1 = (const float*)d_in[6];
  const float* wp_b1 = (const float*)d_in[7];
  const float* wp_lng= (const float*)d_in[8];
  const float* wp_lnb= (const float*)d_in[9];
  const float* wp_w2 = (const float*)d_in[10];
  const float* wp_b2 = (const float*)d_in[11];
  const float* wp_w3 = (const float*)d_in[12];
  const float* wp_b3 = (const float*)d_in[13];
  const float* w_temp= (const float*)d_in[14];
  const float* w_out = (const float*)d_in[15];
  const float* b_out = (const float*)d_in[16];

  char* ws = (char*)d_ws;
  double* dsumH = (double*)(ws + O_DSUMH);
  double* dsumE = (double*)(ws + O_DSUME);
  float* scal  = (float*)(ws + O_SCAL);
  float* coef  = (float*)(ws + O_COEF);
  float* W     = (float*)(ws + O_W);
  float* rq1   = (float*)(ws + O_RQ1);
  float* rq2   = (float*)(ws + O_RQ2);
  float* mqp   = (float*)(ws + O_MQ);
  float* qdmk  = (float*)(ws + O_QDMK);
  float* rk1   = (float*)(ws + O_RK1);
  float* rk2   = (float*)(ws + O_RK2);
  float* ks2   = (float*)(ws + O_KS2);
  float* marg  = (float*)(ws + O_MARG);
  float* rcs   = (float*)(ws + O_RCS);
  float* rcov  = (float*)(ws + O_RCOV);
  float* mk    = (float*)(ws + O_MK);
  float* qcol  = (float*)(ws + O_QCOL);
  float* lnst  = (float*)(ws + O_LNST);
  __bf16* qhi  = (__bf16*)(ws + O_QHI);
  __bf16* qlo  = (__bf16*)(ws + O_QLO);
  __bf16* khi  = (__bf16*)(ws + O_KHI);
  __bf16* klo  = (__bf16*)(ws + O_KLO);
  __bf16* vth  = (__bf16*)(ws + O_VTH);
  __bf16* vtl  = (__bf16*)(ws + O_VTL);
  __bf16* wth  = (__bf16*)(ws + O_WTH);
  __bf16* wtl  = (__bf16*)(ws + O_WTL);
  __bf16* outh = (__bf16*)(ws + O_OUTH);
  __bf16* outl = (__bf16*)(ws + O_OUTL);
  __bf16* woth = (__bf16*)(ws + O_WOTH);
  __bf16* wotl = (__bf16*)(ws + O_WOTL);
  float* outf  = (float*)d_out;

  hipMemsetAsync(ws + O_DSUMH, 0, 2048, stream);

  transpose_split_kernel<<<dim3(16,16),256,0,stream>>>(w_in,  wth, wtl);
  transpose_split_kernel<<<dim3(16,16),256,0,stream>>>(w_out, woth, wotl);
  ln_stats_kernel<<<dim3(4096,3),256,0,stream>>>(q, k, v, lnst);

  proj_gemm_kernel<<<dim3(16,32,3),256,0,stream>>>(q, k, v, lnst, ln_g, ln_b, wth, wtl,
                                                   qhi, qlo, khi, klo, vth, vtl);

  kstats_kernel<<<128,256,0,stream>>>(khi, klo, mk, rk1, rk2, ks2);
  qstats_kernel<<<128,256,0,stream>>>(qhi, qlo, mk, rq1, rq2, mqp, qdmk, qcol);
  mlp_kernel<<<16,64,0,stream>>>(qcol,mk,wp_w1,wp_b1,wp_lng,wp_lnb,wp_w2,wp_b2,wp_w3,wp_b3,w_temp,W);

  s1_mfma_kernel<<<dim3(8,128),256,0,stream>>>(qhi,qlo,khi,klo,rq1,rq2,mqp,qdmk,rk1,rk2,ks2,
                                               dsumH,marg,rcs,rcov);
  margfin_kernel<<<64,256,0,stream>>>(marg, dsumE);
  scalars1_kernel<<<1,1,0,stream>>>(dsumH, dsumE, W, coef);
  rowfold_kernel<<<256,256,0,stream>>>(marg, rcs, rcov, coef, dsumE);
  scalars2_kernel<<<1,1,0,stream>>>(dsumE, scal);

  s3_mfma_kernel<<<dim3(16,128),512,0,stream>>>(qhi,qlo,khi,klo,vth,vtl,
                                                rq1,mqp,qdmk,rk1,ks2,marg,coef,scal,outh,outl);
  final_gemm_kernel<<<dim3(16,32),256,0,stream>>>(outh, outl, woth, wotl, b_out, outf);
}

// Round 16
// 323.412 us; speedup vs baseline: 1.0368x; 1.0368x over previous
//
#include <hip/hip_runtime.h>
#include <math.h>

// ---------------- problem constants ----------------
#define NHEADS 16
#define DHEAD  64
#define NDIM   1024
#define NB     8
#define NSEQ   512
#define NROWS  4096
#define NHB    128
#define NTOTD  33554432.0    // 16*8*512*512

typedef __bf16 bf16x8 __attribute__((ext_vector_type(8)));
typedef __bf16 bf16x4 __attribute__((ext_vector_type(4)));
typedef float  f32x4  __attribute__((ext_vector_type(4)));

#define MFMA(a,b,c) __builtin_amdgcn_mfma_f32_16x16x32_bf16(a,b,c,0,0,0)

// Q/K fragment-order index: [hb][n>>4][d>>3][n&15][d&7]
static __device__ __forceinline__ size_t qk_off(int hbq, int n, int d){
  return ((size_t)hbq*32 + (n>>4))*1024 + (size_t)(d>>3)*128 + (size_t)(n&15)*8 + (d&7);
}

// ---------------- workspace byte offsets ----------------
#define O_DSUMH  0           // [16][5] doubles
#define O_DSUME  1024        // [4] doubles
#define O_SCAL   2048
#define O_COEF   3072
#define O_W      4096
#define O_RQ1    131072      // f32 [65536] each
#define O_RQ2    393216
#define O_MQ     655360
#define O_QDMK   917504
#define O_RK1    1179648
#define O_RK2    1441792
#define O_KS2    1703936
#define O_MARG   1966080
#define O_RCS    2228224
#define O_RCOV   2490368
#define O_MK     2752512     // f32 [128][64]
#define O_QCOL   2785280     // f32 [128][64]
#define O_QHI    4194304     // bf16 fragment-order, 8 MB each
#define O_QLO    12582912
#define O_KHI    20971520
#define O_KLO    29360128
#define O_VTH    37748736    // bf16 fragment-order V [128][4][16][64][8]
#define O_VTL    46137344
#define O_LNST   54525952    // f32 [3][4096][2]
#define O_WTH    71303168    // bf16 [1024][1024] = 2 MB each
#define O_WTL    73400320
#define O_OUTH   75497472    // bf16 [4096][1024]
#define O_OUTL   83886080
#define O_WOTH   92274688
#define O_WOTL   94371840
// end = 96468992 (~92 MB)

static __device__ __forceinline__ float clamp98(float x){ return fminf(fmaxf(x,-0.98f),0.98f); }

// ---------------- LN row stats for q/k/v (mu, rstd) ----------------
__global__ __launch_bounds__(256) void ln_stats_kernel(const float* __restrict__ q,
    const float* __restrict__ k, const float* __restrict__ v, float* __restrict__ st){
  int row = blockIdx.x, t = threadIdx.x;
  const float* x = (blockIdx.y==0) ? q : (blockIdx.y==1 ? k : v);
  float4 vv = *(const float4*)(x + (size_t)row*1024 + t*4);
  float s  = vv.x+vv.y+vv.z+vv.w;
  float ss = vv.x*vv.x+vv.y*vv.y+vv.z*vv.z+vv.w*vv.w;
  for (int off=32; off; off>>=1){ s += __shfl_down(s,off); ss += __shfl_down(ss,off); }
  __shared__ float sh[8];
  if ((t&63)==0){ sh[t>>6]=s; sh[4+(t>>6)]=ss; }
  __syncthreads();
  if (t==0){
    float S=sh[0]+sh[1]+sh[2]+sh[3], SS=sh[4]+sh[5]+sh[6]+sh[7];
    float mu = S*(1.0f/1024.0f);
    st[blockIdx.y*8192 + row*2]   = mu;
    st[blockIdx.y*8192 + row*2+1] = 1.0f/sqrtf(SS*(1.0f/1024.0f) - mu*mu + 1e-5f);
  }
}

// ---------------- transpose + split both weights (z: 0=w_in 1=w_out) ----------------
__global__ __launch_bounds__(256) void transpose_split_kernel(
    const float* __restrict__ w0, const float* __restrict__ w1,
    __bf16* __restrict__ th0, __bf16* __restrict__ tl0,
    __bf16* __restrict__ th1, __bf16* __restrict__ tl1){
  const float* wsrc = blockIdx.z ? w1 : w0;
  __bf16* th = blockIdx.z ? th1 : th0;
  __bf16* tl = blockIdx.z ? tl1 : tl0;
  __shared__ float tile[64][65];
  int k0 = blockIdx.x*64, n0 = blockIdx.y*64;
  int t = threadIdx.x;
  int c = t&63, r4 = t>>6;
  #pragma unroll
  for (int i=0;i<16;i++){
    int kr = r4 + i*4;
    tile[kr][c] = wsrc[(size_t)(k0+kr)*1024 + n0 + c];
  }
  __syncthreads();
  #pragma unroll
  for (int i=0;i<16;i++){
    int nr = r4 + i*4;
    float v = tile[c][nr];
    __bf16 hv = (__bf16)v;
    size_t o = (size_t)(n0+nr)*1024 + k0 + c;
    th[o] = hv; tl[o] = (__bf16)(v - (float)hv);
  }
}

// ---------------- merged proj GEMM (LN fused, software-pipelined loads) ----------------
// z: 0=Q 1=K (frag-order) 2=V (frag-order V). Pad 68, 52.2KB LDS.
__global__ __launch_bounds__(256) void proj_gemm_kernel(
  const float* __restrict__ q, const float* __restrict__ k, const float* __restrict__ v,
  const float* __restrict__ lnst0,
  const float* __restrict__ gv, const float* __restrict__ bv,
  const __bf16* __restrict__ Bth, const __bf16* __restrict__ Btl,
  __bf16* __restrict__ qhi, __bf16* __restrict__ qlo,
  __bf16* __restrict__ khi, __bf16* __restrict__ klo,
  __bf16* __restrict__ vth, __bf16* __restrict__ vtl)
{
  __shared__ __bf16 Ash[128][68];
  __shared__ __bf16 Asl[128][68];
  __shared__ __bf16 Bsh[64][68];
  __shared__ __bf16 Bsl[64][68];
  int z = blockIdx.z;
  const float* X = (z==0)? q : (z==1? k : v);
  const float* lnst = lnst0 + z*8192;
  __bf16* oh = (z==0)? qhi : (z==1? khi : vth);
  __bf16* ol = (z==0)? qlo : (z==1? klo : vtl);
  int t = threadIdx.x, w = t>>6, lane = t&63, lr = lane&15, lq = lane>>4;
  int vid = blockIdx.y*16 + blockIdx.x;
  int cX = vid&7, r2 = vid>>3;
  int ytile = cX*4 + (r2>>4);
  int xtile = r2&15;
  int rbase = ytile*128;
  int cbase = xtile*64;
  int wr = w>>1, wc = w&1;
  int srow = t>>3;
  int scol = (t&7)*8;
  // per-row LN constants (fixed across kt)
  float muv[4], rsv[4];
  #pragma unroll
  for (int r=0;r<4;r++){
    int row = rbase + r*32 + srow;
    muv[r] = lnst[row*2]; rsv[r] = lnst[row*2+1];
  }
  f32x4 acc[4][2] = {};
  // prologue: load tile 0
  float4 xlo[4], xhi[4];
  bf16x8 pb[2], pB[2];
  #pragma unroll
  for (int r=0;r<4;r++){
    size_t gi = (size_t)(rbase + r*32 + srow)*1024 + scol;
    xlo[r] = *(const float4*)(X + gi);
    xhi[r] = *(const float4*)(X + gi + 4);
  }
  #pragma unroll
  for (int r=0;r<2;r++){
    size_t gi = (size_t)(cbase + r*32 + srow)*1024 + scol;
    pb[r] = *(const bf16x8*)(Bth + gi);
    pB[r] = *(const bf16x8*)(Btl + gi);
  }
  for (int kt=0; kt<16; kt++){
    int k0 = kt*64;
    float4 g0 = *(const float4*)(gv + k0 + scol);
    float4 g1 = *(const float4*)(gv + k0 + scol + 4);
    float4 b0 = *(const float4*)(bv + k0 + scol);
    float4 b1 = *(const float4*)(bv + k0 + scol + 4);
    #pragma unroll
    for (int r=0;r<4;r++){
      float mu = muv[r], rs = rsv[r];
      float o[8];
      o[0]=(xlo[r].x-mu)*rs*g0.x+b0.x; o[1]=(xlo[r].y-mu)*rs*g0.y+b0.y;
      o[2]=(xlo[r].z-mu)*rs*g0.z+b0.z; o[3]=(xlo[r].w-mu)*rs*g0.w+b0.w;
      o[4]=(xhi[r].x-mu)*rs*g1.x+b1.x; o[5]=(xhi[r].y-mu)*rs*g1.y+b1.y;
      o[6]=(xhi[r].z-mu)*rs*g1.z+b1.z; o[7]=(xhi[r].w-mu)*rs*g1.w+b1.w;
      bf16x8 hv, lv;
      #pragma unroll
      for (int e=0;e<8;e++){
        __bf16 hb_ = (__bf16)o[e];
        hv[e] = hb_; lv[e] = (__bf16)(o[e]-(float)hb_);
      }
      *(bf16x8*)&Ash[r*32+srow][scol] = hv;
      *(bf16x8*)&Asl[r*32+srow][scol] = lv;
    }
    #pragma unroll
    for (int r=0;r<2;r++){
      *(bf16x8*)&Bsh[r*32+srow][scol] = pb[r];
      *(bf16x8*)&Bsl[r*32+srow][scol] = pB[r];
    }
    __syncthreads();
    // prefetch kt+1 while MFMAs run
    if (kt<15){
      int k1 = k0 + 64;
      #pragma unroll
      for (int r=0;r<4;r++){
        size_t gi = (size_t)(rbase + r*32 + srow)*1024 + k1 + scol;
        xlo[r] = *(const float4*)(X + gi);
        xhi[r] = *(const float4*)(X + gi + 4);
      }
      #pragma unroll
      for (int r=0;r<2;r++){
        size_t gi = (size_t)(cbase + r*32 + srow)*1024 + k1 + scol;
        pb[r] = *(const bf16x8*)(Bth + gi);
        pB[r] = *(const bf16x8*)(Btl + gi);
      }
    }
    #pragma unroll
    for (int kc=0; kc<2; kc++){
      int ko = kc*32 + lq*8;
      bf16x8 ah[4], al[4], bh[2], bl[2];
      #pragma unroll
      for (int i=0;i<4;i++){
        ah[i] = *(const bf16x8*)&Ash[wr*64 + i*16 + lr][ko];
        al[i] = *(const bf16x8*)&Asl[wr*64 + i*16 + lr][ko];
      }
      #pragma unroll
      for (int j=0;j<2;j++){
        bh[j] = *(const bf16x8*)&Bsh[wc*32 + j*16 + lr][ko];
        bl[j] = *(const bf16x8*)&Bsl[wc*32 + j*16 + lr][ko];
      }
      #pragma unroll
      for (int i=0;i<4;i++)
        #pragma unroll
        for (int j=0;j<2;j++){
          acc[i][j] = MFMA(al[i], bh[j], acc[i][j]);
          acc[i][j] = MFMA(ah[i], bl[j], acc[i][j]);
          acc[i][j] = MFMA(ah[i], bh[j], acc[i][j]);
        }
    }
    __syncthreads();
  }
  // epilogue
  #pragma unroll
  for (int i=0;i<4;i++)
    #pragma unroll
    for (int j=0;j<2;j++)
      #pragma unroll
      for (int r=0;r<4;r++){
        int row = rbase + wr*64 + i*16 + lq*4 + r;
        int col = cbase + wc*32 + j*16 + lr;
        float val = acc[i][j][r];
        __bf16 hv = (__bf16)val;
        __bf16 lv = (__bf16)(val - (float)hv);
        int n = row & 511, b2 = row >> 9;
        int hh = col >> 6, d = col & 63;
        int hbq = hh*8 + b2;
        size_t o;
        if (z<2){
          o = qk_off(hbq, n, d);
        } else {
          o = (((size_t)hbq*4 + (d>>4))*16 + (n>>5))*512
            + (size_t)((((n>>3)&3)*16) + (d&15))*8 + (n&7);
        }
        oh[o] = hv; ol[o] = lv;
      }
}

// ---------------- final GEMM (LDS-staged, software-pipelined loads) ----------------
__global__ __launch_bounds__(256) void final_gemm_kernel(
  const __bf16* __restrict__ Ah, const __bf16* __restrict__ Al,
  const __bf16* __restrict__ Bth, const __bf16* __restrict__ Btl,
  const float* __restrict__ bias, float* __restrict__ of)
{
  __shared__ __bf16 Ash[128][68];
  __shared__ __bf16 Asl[128][68];
  __shared__ __bf16 Bsh[64][68];
  __shared__ __bf16 Bsl[64][68];
  int t = threadIdx.x, w = t>>6, lane = t&63, lr = lane&15, lq = lane>>4;
  int vid = blockIdx.y*16 + blockIdx.x;
  int cX = vid&7, r2 = vid>>3;
  int ytile = cX*4 + (r2>>4);
  int xtile = r2&15;
  int rbase = ytile*128;
  int cbase = xtile*64;
  int wr = w>>1, wc = w&1;
  int srow = t>>3;
  int scol = (t&7)*8;
  f32x4 acc[4][2] = {};
  bf16x8 pa[4], pA[4], pb[2], pB[2];
  #pragma unroll
  for (int r=0;r<4;r++){
    size_t gi = (size_t)(rbase + r*32 + srow)*1024 + scol;
    pa[r] = *(const bf16x8*)(Ah + gi);
    pA[r] = *(const bf16x8*)(Al + gi);
  }
  #pragma unroll
  for (int r=0;r<2;r++){
    size_t gi = (size_t)(cbase + r*32 + srow)*1024 + scol;
    pb[r] = *(const bf16x8*)(Bth + gi);
    pB[r] = *(const bf16x8*)(Btl + gi);
  }
  for (int kt=0; kt<16; kt++){
    int k0 = kt*64;
    #pragma unroll
    for (int r=0;r<4;r++){
      *(bf16x8*)&Ash[r*32+srow][scol] = pa[r];
      *(bf16x8*)&Asl[r*32+srow][scol] = pA[r];
    }
    #pragma unroll
    for (int r=0;r<2;r++){
      *(bf16x8*)&Bsh[r*32+srow][scol] = pb[r];
      *(bf16x8*)&Bsl[r*32+srow][scol] = pB[r];
    }
    __syncthreads();
    if (kt<15){
      int k1 = k0 + 64;
      #pragma unroll
      for (int r=0;r<4;r++){
        size_t gi = (size_t)(rbase + r*32 + srow)*1024 + k1 + scol;
        pa[r] = *(const bf16x8*)(Ah + gi);
        pA[r] = *(const bf16x8*)(Al + gi);
      }
      #pragma unroll
      for (int r=0;r<2;r++){
        size_t gi = (size_t)(cbase + r*32 + srow)*1024 + k1 + scol;
        pb[r] = *(const bf16x8*)(Bth + gi);
        pB[r] = *(const bf16x8*)(Btl + gi);
      }
    }
    #pragma unroll
    for (int kc=0; kc<2; kc++){
      int ko = kc*32 + lq*8;
      bf16x8 ah[4], al[4], bh[2], bl[2];
      #pragma unroll
      for (int i=0;i<4;i++){
        ah[i] = *(const bf16x8*)&Ash[wr*64 + i*16 + lr][ko];
        al[i] = *(const bf16x8*)&Asl[wr*64 + i*16 + lr][ko];
      }
      #pragma unroll
      for (int j=0;j<2;j++){
        bh[j] = *(const bf16x8*)&Bsh[wc*32 + j*16 + lr][ko];
        bl[j] = *(const bf16x8*)&Bsl[wc*32 + j*16 + lr][ko];
      }
      #pragma unroll
      for (int i=0;i<4;i++)
        #pragma unroll
        for (int j=0;j<2;j++){
          acc[i][j] = MFMA(al[i], bh[j], acc[i][j]);
          acc[i][j] = MFMA(ah[i], bl[j], acc[i][j]);
          acc[i][j] = MFMA(ah[i], bh[j], acc[i][j]);
        }
    }
    __syncthreads();
  }
  #pragma unroll
  for (int i=0;i<4;i++)
    #pragma unroll
    for (int j=0;j<2;j++)
      #pragma unroll
      for (int r=0;r<4;r++){
        int row = rbase + wr*64 + i*16 + lq*4 + r;
        int col = cbase + wc*32 + j*16 + lr;
        of[(size_t)row*1024 + col] = acc[i][j][r] + bias[col];
      }
}

// ---------------- per-(h,b) key stats (fragment-order input) ----------------
__global__ void kstats_kernel(const __bf16* __restrict__ kh, const __bf16* __restrict__ kl,
    float* __restrict__ mk, float* __restrict__ rk1, float* __restrict__ rk2, float* __restrict__ ks2){
  int hb = blockIdx.x;
  size_t base = (size_t)hb*32768;
  int t = threadIdx.x;
  __shared__ float csA[32][64];
  __shared__ float mks_lds[64];
  __shared__ float mksum_sh;
  int c2 = t&7, mg = t>>3;
  float fs[8] = {};
  for (int m=mg; m<512; m+=32){
    size_t off = base + (size_t)(m>>4)*1024 + c2*128 + (size_t)(m&15)*8;
    bf16x8 h = *(const bf16x8*)(kh+off);
    bf16x8 l = *(const bf16x8*)(kl+off);
    #pragma unroll
    for (int e=0;e<8;e++) fs[e] += (float)h[e]+(float)l[e];
  }
  #pragma unroll
  for (int e=0;e<8;e++) csA[mg][c2*8+e] = fs[e];
  __syncthreads();
  if (t<64){
    float s=0;
    #pragma unroll
    for (int g=0;g<32;g++) s += csA[g][t];
    float vv = s*(1.0f/512.0f);
    mk[hb*64+t] = vv;
    mks_lds[t] = vv;
  }
  __syncthreads();
  if (t==0){
    float s=0;
    for (int i=0;i<64;i++) s += mks_lds[i];
    mksum_sh = s;
  }
  __syncthreads();
  float mks = mksum_sh;
  int l8 = t&7, rg = t>>3;
  for (int m=rg; m<512; m+=32){
    size_t off = base + (size_t)(m>>4)*1024 + l8*128 + (size_t)(m&15)*8;
    bf16x8 h = *(const bf16x8*)(kh+off);
    bf16x8 l = *(const bf16x8*)(kl+off);
    float s=0, ss=0;
    #pragma unroll
    for (int e=0;e<8;e++){ float vv=(float)h[e]+(float)l[e]; s+=vv; ss+=vv*vv; }
    for (int o2=4;o2;o2>>=1){ s+=__shfl_xor(s,o2); ss+=__shfl_xor(ss,o2); }
    if (l8==0){
      float nk = sqrtf(ss);
      rk1[hb*512+m] = 1.0f/(nk+1e-8f);
      rk2[hb*512+m] = 1.0f/fmaxf(nk,1e-6f);
      ks2[hb*512+m] = s - mks;
    }
  }
}

// ---------------- per-(h,b) query stats (fragment-order input) ----------------
__global__ void qstats_kernel(const __bf16* __restrict__ qh, const __bf16* __restrict__ ql,
    const float* __restrict__ mk, float* __restrict__ rq1, float* __restrict__ rq2,
    float* __restrict__ mq, float* __restrict__ qdotmk, float* __restrict__ qcol){
  int hb = blockIdx.x;
  size_t base = (size_t)hb*32768;
  int t = threadIdx.x;
  __shared__ float csA[32][64];
  __shared__ float mks_lds[64];
  int c2 = t&7, mg = t>>3;
  if (t<64) mks_lds[t] = mk[hb*64+t];
  float fs[8] = {};
  for (int m=mg; m<512; m+=32){
    size_t off = base + (size_t)(m>>4)*1024 + c2*128 + (size_t)(m&15)*8;
    bf16x8 h = *(const bf16x8*)(qh+off);
    bf16x8 l = *(const bf16x8*)(ql+off);
    #pragma unroll
    for (int e=0;e<8;e++) fs[e] += (float)h[e]+(float)l[e];
  }
  #pragma unroll
  for (int e=0;e<8;e++) csA[mg][c2*8+e] = fs[e];
  __syncthreads();
  if (t<64){
    float s=0;
    #pragma unroll
    for (int g=0;g<32;g++) s += csA[g][t];
    qcol[hb*64+t] = s;
  }
  int l8 = t&7, rg = t>>3;
  float mkv[8];
  #pragma unroll
  for (int e=0;e<8;e++) mkv[e] = mks_lds[l8*8+e];
  for (int n=rg; n<512; n+=32){
    size_t off = base + (size_t)(n>>4)*1024 + l8*128 + (size_t)(n&15)*8;
    bf16x8 h = *(const bf16x8*)(qh+off);
    bf16x8 l = *(const bf16x8*)(ql+off);
    float s=0, ss=0, qd=0;
    #pragma unroll
    for (int e=0;e<8;e++){
      float vv=(float)h[e]+(float)l[e];
      s+=vv; ss+=vv*vv; qd+=vv*mkv[e];
    }
    for (int o2=4;o2;o2>>=1){ s+=__shfl_xor(s,o2); ss+=__shfl_xor(ss,o2); qd+=__shfl_xor(qd,o2); }
    if (l8==0){
      float nq = sqrtf(ss);
      rq1[hb*512+n] = 1.0f/(nq+1e-8f);
      rq2[hb*512+n] = 1.0f/fmaxf(nq,1e-6f);
      mq[hb*512+n]  = s*(1.0f/64.0f);
      qdotmk[hb*512+n] = qd;
    }
  }
}

// ---------------- per-head weight MLP ----------------
__global__ void mlp_kernel(const float* __restrict__ qcol, const float* __restrict__ mk,
   const float* __restrict__ w1, const float* __restrict__ b1, const float* __restrict__ lng,
   const float* __restrict__ lnb, const float* __restrict__ w2, const float* __restrict__ b2,
   const float* __restrict__ w3, const float* __restrict__ b3, const float* __restrict__ wtemp,
   float* __restrict__ W){
  int h = blockIdx.x;
  int j = threadIdx.x;
  __shared__ float qk[128], h1[64], h2[32];
  float sq=0, sk=0;
  #pragma unroll
  for (int b=0;b<8;b++){
    sq += qcol[(h*8+b)*64 + j];
    sk += mk[(h*8+b)*64 + j];
  }
  qk[j]    = sq*(1.0f/4096.0f);
  qk[64+j] = sk*(1.0f/8.0f);
  __syncthreads();
  float a = b1[j];
  for (int i=0;i<128;i++) a += qk[i]*w1[i*64+j];
  float s=a, ss=a*a;
  for (int off=32; off; off>>=1){ s += __shfl_xor(s,off); ss += __shfl_xor(ss,off); }
  float mu = s*(1.0f/64.0f), var = ss*(1.0f/64.0f)-mu*mu;
  float v = (a-mu)/sqrtf(var+1e-5f)*lng[j] + lnb[j];
  h1[j] = fmaxf(v, 0.0f);
  __syncthreads();
  if (j<32){
    float a2 = b2[j];
    for (int i=0;i<64;i++) a2 += h1[i]*w2[i*32+j];
    h2[j] = fmaxf(a2,0.0f);
  }
  __syncthreads();
  if (j==0){
    float l[3];
    for (int kq=0;kq<3;kq++){ float a3=b3[kq]; for(int i=0;i<32;i++) a3 += h2[i]*w3[i*3+kq]; l[kq]=a3; }
    float m = fmaxf(l[0],fmaxf(l[1],l[2]));
    float e0=expf(l[0]-m), e1=expf(l[1]-m), e2=expf(l[2]-m);
    float si = 1.0f/(e0+e1+e2);
    float temp = fminf(fmaxf(wtemp[0], 0.1f), 5.0f);
    float t0=e0*si/temp, t1=e1*si/temp, t2=e2*si/temp;
    float m2 = fmaxf(t0,fmaxf(t1,t2));
    float f0=expf(t0-m2), f1=expf(t1-m2), f2=expf(t2-m2);
    float s2i = 1.0f/(f0+f1+f2);
    float wv[3] = {f0*s2i, f1*s2i, f2*s2i};
    float wsum=0.0f;
    for (int kq=0;kq<3;kq++){ wv[kq]=fminf(fmaxf(wv[kq],0.08f),0.75f); wsum+=wv[kq]; }
    for (int kq=0;kq<3;kq++) W[h*3+kq] = wv[kq]/wsum;
  }
}

// ---------------- S1 v3 (MFMA): 64-row blocks for occupancy, wave tile 16x512 ----------------
__global__ __launch_bounds__(256) void s1_mfma_kernel(
  const __bf16* __restrict__ qhp, const __bf16* __restrict__ qlp,
  const __bf16* __restrict__ khp, const __bf16* __restrict__ klp,
  const float* __restrict__ rq1, const float* __restrict__ rq2,
  const float* __restrict__ mq, const float* __restrict__ qdmk,
  const float* __restrict__ rk1, const float* __restrict__ rk2,
  const float* __restrict__ ks2,
  double* __restrict__ dsumH, float* __restrict__ margin,
  float* __restrict__ rcs, float* __restrict__ rcov)
{
  int vid = blockIdx.y*8 + blockIdx.x;
  int cX = vid&7, r2 = vid>>3;       // r2: 0..127
  int hb = cX*16 + (r2>>3);
  int n0 = (r2&7)*64;
  size_t qb = (size_t)hb*32768;
  __shared__ float sm[512][3];
  __shared__ float sn[64][4];
  int t = threadIdx.x;
  for (int mm=t; mm<512; mm+=256){
    int m = hb*512 + mm;
    sm[mm][0]=rk1[m]; sm[mm][1]=rk2[m]; sm[mm][2]=ks2[m];
  }
  if (t<64){
    int n = hb*512 + n0 + t;
    sn[t][0]=rq1[n]; sn[t][1]=rq2[n]; sn[t][2]=mq[n]; sn[t][3]=qdmk[n];
  }
  __syncthreads();
  int w = t>>6, lane = t&63, lr = lane&15, lq = lane>>4;
  int nw = w*16;
  float lcs=0,lcs2=0,lcov=0,lcov2=0,lcscov=0;
  float mrow[4]={}, csr[4]={}, cvr[4]={};
  float nr1[4],nr2[4],nmq[4],nqd[4];
  #pragma unroll
  for (int r=0;r<4;r++){
    int nl = nw + lq*4 + r;
    nr1[r]=sn[nl][0]; nr2[r]=sn[nl][1]; nmq[r]=sn[nl][2]; nqd[r]=sn[nl][3];
  }
  for (int mc=0; mc<4; mc++){
    int m0 = mc*128;
    f32x4 acc[8] = {};
    #pragma unroll
    for (int kc=0; kc<2; kc++){
      size_t qoff = qb + (size_t)((n0+nw)>>4)*1024 + kc*512 + (size_t)lane*8;
      bf16x8 ah = *(const bf16x8*)(qhp + qoff);
      bf16x8 al = *(const bf16x8*)(qlp + qoff);
      #pragma unroll
      for (int j=0;j<8;j++){
        size_t off = qb + (size_t)((m0>>4)+j)*1024 + kc*512 + (size_t)lane*8;
        bf16x8 bh = *(const bf16x8*)(khp + off);
        bf16x8 bl = *(const bf16x8*)(klp + off);
        acc[j] = MFMA(ah, bh, acc[j]);
        acc[j] = MFMA(ah, bl, acc[j]);
        acc[j] = MFMA(al, bh, acc[j]);
      }
    }
    #pragma unroll
    for (int j=0;j<8;j++){
      int ml = m0 + j*16 + lr;
      float k1=sm[ml][0], k2=sm[ml][1], ksv=sm[ml][2];
      #pragma unroll
      for (int r=0;r<4;r++){
        float dv = acc[j][r];
        float cs = clamp98(dv*nr1[r]*k1);
        float c2 = clamp98(dv*nr2[r]*k2);
        float mg = fminf(fmaxf(0.01f-c2,0.0f),5.0f);
        float cv = dv - nqd[r] - nmq[r]*ksv;
        lcs+=cs; lcs2+=cs*cs; lcov+=cv; lcov2+=cv*cv; lcscov+=cs*cv;
        mrow[r]+=mg; csr[r]+=cs; cvr[r]+=cv;
      }
    }
  }
  for (int off=1; off<16; off<<=1)
    #pragma unroll
    for (int r=0;r<4;r++){
      mrow[r]+=__shfl_xor(mrow[r],off);
      csr[r] +=__shfl_xor(csr[r],off);
      cvr[r]+=__shfl_xor(cvr[r],off);
    }
  if (lr==0){
    #pragma unroll
    for (int r=0;r<4;r++){
      int n = hb*512 + n0 + nw + lq*4 + r;
      margin[n] = mrow[r]*(1.0f/512.0f);
      rcs[n]    = csr[r];
      rcov[n]   = cvr[r];
    }
  }
  for (int off=32; off; off>>=1){
    lcs+=__shfl_xor(lcs,off); lcs2+=__shfl_xor(lcs2,off);
    lcov+=__shfl_xor(lcov,off); lcov2+=__shfl_xor(lcov2,off);
    lcscov+=__shfl_xor(lcscov,off);
  }
  __shared__ double red[4][5];
  if (lane==0){ red[w][0]=lcs; red[w][1]=lcs2; red[w][2]=lcov; red[w][3]=lcov2; red[w][4]=lcscov; }
  __syncthreads();
  if (t==0){
    int h = hb>>3;
    for (int c=0;c<5;c++)
      atomicAdd(&dsumH[h*5+c], red[0][c]+red[1][c]+red[2][c]+red[3][c]);
  }
}

// ---------------- var_c moments ----------------
__global__ void margfin_kernel(const float* __restrict__ margin, double* __restrict__ dsumE){
  double s=0, ss=0;
  for (int k2=0;k2<4;k2++){
    int idx = blockIdx.x*1024 + k2*256 + threadIdx.x;
    float v = margin[idx];
    s += v; ss += (double)v*v;
  }
  for (int off=32; off; off>>=1){ s+=__shfl_down(s,off); ss+=__shfl_down(ss,off); }
  __shared__ double sh[8];
  int t = threadIdx.x;
  if ((t&63)==0){ sh[t>>6]=s; sh[4+(t>>6)]=ss; }
  __syncthreads();
  if (t==0){
    atomicAdd(dsumE+0, sh[0]+sh[1]+sh[2]+sh[3]);
    atomicAdd(dsumE+1, sh[4]+sh[5]+sh[6]+sh[7]);
  }
}

// ---------------- fold stats into per-head coefficients ----------------
__global__ void scalars1_kernel(const double* __restrict__ dsumH, double* __restrict__ dsumE,
                                const float* __restrict__ W, float* __restrict__ coef){
  double Scs=0,Scs2=0,Scov=0,Scov2=0;
  for (int h=0;h<16;h++){
    Scs += dsumH[h*5+0]; Scs2 += dsumH[h*5+1];
    Scov += dsumH[h*5+2]; Scov2 += dsumH[h*5+3];
  }
  double N = NTOTD;
  double cn = sqrt(fmax((Scs2-Scs*Scs/N)/(N-1.0),0.0)) + 1e-6;
  double ch = fmin(cn, 1.0);
  const double covscale = 1.0/8.000001;
  double sc_ = Scov*covscale, sc2_ = Scov2*covscale*covscale;
  double health = sqrt(fmax((sc2_-sc_*sc_/N)/(N-1.0),0.0));
  double base = 0.001/512.0;
  double reg = health<1e-5 ? base*5.0 : (health<1e-3 ? base*2.0 : base);
  double covn = reg*health + 1e-6;
  double covh = fmin(covn*10.0, 1.0);
  double vs = dsumE[0]*512.0, vs2 = dsumE[1]*512.0;
  double varn = sqrt(fmax((vs2 - vs*vs/N)/(N-1.0),0.0)) + 1e-6;
  double varh = fmin(varn*10.0, 1.0);
  double sdf=0, sdf2=0;
  for (int h=0;h<16;h++){
    double cC  = (double)W[h*3+0]*ch/cn;
    double cCv = (double)W[h*3+1]*reg*covscale*0.4*covh/covn;
    double cVr = (double)W[h*3+2]*0.4*varh/varn;
    coef[h*3+0] = (float)cC;
    coef[h*3+1] = (float)cCv;
    coef[h*3+2] = (float)cVr;
    sdf  += cC*dsumH[h*5+0] + cCv*dsumH[h*5+2];
    sdf2 += cC*cC*dsumH[h*5+1] + cCv*cCv*dsumH[h*5+3] + 2.0*cC*cCv*dsumH[h*5+4];
  }
  dsumE[2] = sdf;
  dsumE[3] = sdf2;
}

// ---------------- row-level fold of df moments ----------------
__global__ void rowfold_kernel(const float* __restrict__ margin, const float* __restrict__ rcs,
                               const float* __restrict__ rcov, const float* __restrict__ coef,
                               double* __restrict__ dsumE){
  int idx = blockIdx.x*256 + threadIdx.x;
  int h = idx >> 12;
  float cC = coef[h*3+0], cCv = coef[h*3+1], cVr = coef[h*3+2];
  float vc = cVr * margin[idx];
  double s0 = 512.0*(double)vc;
  double s1 = 2.0*(double)vc*((double)cC*(double)rcs[idx] + (double)cCv*(double)rcov[idx])
            + 512.0*(double)vc*(double)vc;
  for (int off=32; off; off>>=1){ s0+=__shfl_down(s0,off); s1+=__shfl_down(s1,off); }
  __shared__ double sh[8];
  int t = threadIdx.x;
  if ((t&63)==0){ sh[t>>6]=s0; sh[4+(t>>6)]=s1; }
  __syncthreads();
  if (t==0){
    atomicAdd(dsumE+2, sh[0]+sh[1]+sh[2]+sh[3]);
    atomicAdd(dsumE+3, sh[4]+sh[5]+sh[6]+sh[7]);
  }
}

// ---------------- finalize adaptive temperature ----------------
__global__ void scalars2_kernel(const double* __restrict__ dsumE, float* __restrict__ scal){
  double N = NTOTD;
  double div = sqrt(fmax((dsumE[3]-dsumE[2]*dsumE[2]/N)/(N-1.0),0.0));
  double at = div<1e-5 ? 0.05 : (div<1e-3 ? 0.2 : 0.5+div);
  at = fmin(fmax(at,0.05),2.0);
  scal[0] = (float)(1.0/at);
}

// ---------------- S3 (MFMA): 32-row blocks + XCD swizzle + frag-order Q/K/V ----------------
#define PSTRIDE 536
__global__ __launch_bounds__(512) void s3_mfma_kernel(
  const __bf16* __restrict__ qhp, const __bf16* __restrict__ qlp,
  const __bf16* __restrict__ khp, const __bf16* __restrict__ klp,
  const __bf16* __restrict__ vth, const __bf16* __restrict__ vtl,
  const float* __restrict__ rq1, const float* __restrict__ mq,
  const float* __restrict__ qdmk, const float* __restrict__ rk1,
  const float* __restrict__ ks2, const float* __restrict__ margin,
  const float* __restrict__ coef, const float* __restrict__ scal,
  __bf16* __restrict__ outh, __bf16* __restrict__ outl)
{
  int vid = blockIdx.y*16 + blockIdx.x;
  int cX = vid&7, r2 = vid>>3;
  int hb = cX*16 + (r2>>4);
  int n0 = (r2&15)*32;
  int h = hb>>3, b = hb&7;
  size_t qb = (size_t)hb*32768;

  __shared__ unsigned short Plds[32][PSTRIDE];
  __shared__ float nst[32][4];
  __shared__ float mst[512][2];
  __shared__ float pmax[32][8];
  __shared__ float psum[32][8];

  int t = threadIdx.x, w = t>>6, lane = t&63, lr = lane&15, lq = lane>>4;
  if (t<32){
    int n = hb*512 + n0 + t;
    nst[t][0] = rq1[n]; nst[t][1] = mq[n]; nst[t][2] = qdmk[n];
    nst[t][3] = coef[h*3+2]*margin[n];
  }
  {
    int m = hb*512 + t;
    mst[t][0] = rk1[m]; mst[t][1] = ks2[m];
  }
  float cC = coef[h*3+0], cCv = coef[h*3+1];
  float invat = scal[0];
  __syncthreads();

  int ms0 = w*64;
  f32x4 acc[2][4] = {};
  #pragma unroll
  for (int kc=0; kc<2; kc++){
    bf16x8 qhf[2], qlf[2];
    #pragma unroll
    for (int i=0;i<2;i++){
      size_t off = qb + (size_t)((n0>>4)+i)*1024 + kc*512 + (size_t)lane*8;
      qhf[i] = *(const bf16x8*)(qhp + off);
      qlf[i] = *(const bf16x8*)(qlp + off);
    }
    #pragma unroll
    for (int j=0;j<4;j++){
      size_t off = qb + (size_t)((ms0>>4)+j)*1024 + kc*512 + (size_t)lane*8;
      bf16x8 khf = *(const bf16x8*)(khp + off);
      bf16x8 klf = *(const bf16x8*)(klp + off);
      #pragma unroll
      for (int i=0;i<2;i++){
        acc[i][j] = MFMA(qlf[i], khf, acc[i][j]);
        acc[i][j] = MFMA(qhf[i], klf, acc[i][j]);
        acc[i][j] = MFMA(qhf[i], khf, acc[i][j]);
      }
    }
  }
  float rmax[2][4];
  #pragma unroll
  for (int i=0;i<2;i++){
    float a0[4],a1[4],a2[4],a3[4];
    #pragma unroll
    for (int r=0;r<4;r++){
      int nl = i*16 + lq*4 + r;
      a0[r]=nst[nl][0]; a1[r]=nst[nl][1]; a2[r]=nst[nl][2]; a3[r]=nst[nl][3];
      rmax[i][r] = -1e30f;
    }
    #pragma unroll
    for (int j=0;j<4;j++){
      int m = ms0 + j*16 + lr;
      float k1 = mst[m][0], ksv = mst[m][1];
      #pragma unroll
      for (int r=0;r<4;r++){
        float dv = acc[i][j][r];
        float cs = clamp98(dv*a0[r]*k1);
        float covr = dv - a2[r] - a1[r]*ksv;
        float df = cC*cs + cCv*covr + a3[r];
        acc[i][j][r] = df;
        rmax[i][r] = fmaxf(rmax[i][r], df);
      }
    }
  }
  #pragma unroll
  for (int i=0;i<2;i++)
    #pragma unroll
    for (int r=0;r<4;r++)
      for (int off=1; off<16; off<<=1)
        rmax[i][r] = fmaxf(rmax[i][r], __shfl_xor(rmax[i][r], off));
  if (lr==0){
    #pragma unroll
    for (int i=0;i<2;i++)
      #pragma unroll
      for (int r=0;r<4;r++)
        pmax[i*16+lq*4+r][w] = rmax[i][r];
  }
  __syncthreads();
  float rsum[2][4] = {};
  #pragma unroll
  for (int i=0;i<2;i++){
    float Mf[4];
    #pragma unroll
    for (int r=0;r<4;r++){
      int nl = i*16+lq*4+r;
      float m0_ = fmaxf(fmaxf(pmax[nl][0],pmax[nl][1]),fmaxf(pmax[nl][2],pmax[nl][3]));
      float m1_ = fmaxf(fmaxf(pmax[nl][4],pmax[nl][5]),fmaxf(pmax[nl][6],pmax[nl][7]));
      Mf[r] = fmaxf(m0_,m1_);
    }
    #pragma unroll
    for (int j=0;j<4;j++){
      int m = ms0 + j*16 + lr;
      #pragma unroll
      for (int r=0;r<4;r++){
        float p = __expf((acc[i][j][r]-Mf[r])*invat);
        rsum[i][r] += p;
        *(__bf16*)&Plds[i*16+lq*4+r][m] = (__bf16)p;
      }
    }
  }
  #pragma unroll
  for (int i=0;i<2;i++)
    #pragma unroll
    for (int r=0;r<4;r++)
      for (int off=1; off<16; off<<=1)
        rsum[i][r] += __shfl_xor(rsum[i][r], off);
  if (lr==0){
    #pragma unroll
    for (int i=0;i<2;i++)
      #pragma unroll
      for (int r=0;r<4;r++)
        psum[i*16+lq*4+r][w] = rsum[i][r];
  }
  __syncthreads();

  int rt = (w&1)*16;
  int dtg = w>>1;
  f32x4 acc2 = {};
  for (int kc=0; kc<16; kc++){
    bf16x8 pa = *(const bf16x8*)&Plds[rt+lr][kc*32 + lq*8];
    size_t vi = (((size_t)hb*4 + dtg)*16 + kc)*512 + (size_t)lane*8;
    bf16x8 vh = *(const bf16x8*)(vth + vi);
    bf16x8 vl = *(const bf16x8*)(vtl + vi);
    acc2 = MFMA(pa, vl, acc2);
    acc2 = MFMA(pa, vh, acc2);
  }
  float rsinv[4];
  #pragma unroll
  for (int r=0;r<4;r++){
    int nl = rt + lq*4 + r;
    float s0_ = psum[nl][0]+psum[nl][1]+psum[nl][2]+psum[nl][3];
    float s1_ = psum[nl][4]+psum[nl][5]+psum[nl][6]+psum[nl][7];
    rsinv[r] = 1.0f/(s0_+s1_);
  }
  #pragma unroll
  for (int r=0;r<4;r++){
    float o = acc2[r]*rsinv[r];
    int rowg = b*512 + n0 + rt + lq*4 + r;
    int colg = h*64 + dtg*16 + lr;
    size_t oi = (size_t)rowg*1024 + colg;
    __bf16 hv = (__bf16)o;
    outh[oi] = hv;
    outl[oi] = (__bf16)(o - (float)hv);
  }
}

// ---------------- launch ----------------
extern "C" void kernel_launch(void* const* d_in, const int* in_sizes, int n_in,
                              void* d_out, int out_size, void* d_ws, size_t ws_size,
                              hipStream_t stream) {
  (void)in_sizes; (void)n_in; (void)out_size; (void)ws_size;
  const float* q     = (const float*)d_in[0];
  const float* k     = (const float*)d_in[1];
  const float* v     = (const float*)d_in[2];
  const float* ln_g  = (const float*)d_in[3];
  const float* ln_b  = (const float*)d_in[4];
  const float* w_in  = (const float*)d_in[5];
  const float* wp_w1 = (const float*)d_in[6];
  const float* wp_b1 = (const float*)d_in[7];
  const float* wp_lng= (const float*)d_in[8];
  const float* wp_lnb= (const float*)d_in[9];
  const float* wp_w2 = (const float*)d_in[10];
  const float* wp_b2 = (const float*)d_in[11];
  const float* wp_w3 = (const float*)d_in[12];
  const float* wp_b3 = (const float*)d_in[13];
  const float* w_temp= (const float*)d_in[14];
  const float* w_out = (const float*)d_in[15];
  const float* b_out = (const float*)d_in[16];

  char* ws = (char*)d_ws;
  double* dsumH = (double*)(ws + O_DSUMH);
  double* dsumE = (double*)(ws + O_DSUME);
  float* scal  = (float*)(ws + O_SCAL);
  float* coef  = (float*)(ws + O_COEF);
  float* W     = (float*)(ws + O_W);
  float* rq1   = (float*)(ws + O_RQ1);
  float* rq2   = (float*)(ws + O_RQ2);
  float* mqp   = (float*)(ws + O_MQ);
  float* qdmk  = (float*)(ws + O_QDMK);
  float* rk1   = (float*)(ws + O_RK1);
  float* rk2   = (float*)(ws + O_RK2);
  float* ks2   = (float*)(ws + O_KS2);
  float* marg  = (float*)(ws + O_MARG);
  float* rcs   = (float*)(ws + O_RCS);
  float* rcov  = (float*)(ws + O_RCOV);
  float* mk    = (float*)(ws + O_MK);
  float* qcol  = (float*)(ws + O_QCOL);
  float* lnst  = (float*)(ws + O_LNST);
  __bf16* qhi  = (__bf16*)(ws + O_QHI);
  __bf16* qlo  = (__bf16*)(ws + O_QLO);
  __bf16* khi  = (__bf16*)(ws + O_KHI);
  __bf16* klo  = (__bf16*)(ws + O_KLO);
  __bf16* vth  = (__bf16*)(ws + O_VTH);
  __bf16* vtl  = (__bf16*)(ws + O_VTL);
  __bf16* wth  = (__bf16*)(ws + O_WTH);
  __bf16* wtl  = (__bf16*)(ws + O_WTL);
  __bf16* outh = (__bf16*)(ws + O_OUTH);
  __bf16* outl = (__bf16*)(ws + O_OUTL);
  __bf16* woth = (__bf16*)(ws + O_WOTH);
  __bf16* wotl = (__bf16*)(ws + O_WOTL);
  float* outf  = (float*)d_out;

  hipMemsetAsync(ws + O_DSUMH, 0, 2048, stream);

  transpose_split_kernel<<<dim3(16,16,2),256,0,stream>>>(w_in, w_out, wth, wtl, woth, wotl);
  ln_stats_kernel<<<dim3(4096,3),256,0,stream>>>(q, k, v, lnst);

  proj_gemm_kernel<<<dim3(16,32,3),256,0,stream>>>(q, k, v, lnst, ln_g, ln_b, wth, wtl,
                                                   qhi, qlo, khi, klo, vth, vtl);

  kstats_kernel<<<128,256,0,stream>>>(khi, klo, mk, rk1, rk2, ks2);
  qstats_kernel<<<128,256,0,stream>>>(qhi, qlo, mk, rq1, rq2, mqp, qdmk, qcol);
  mlp_kernel<<<16,64,0,stream>>>(qcol,mk,wp_w1,wp_b1,wp_lng,wp_lnb,wp_w2,wp_b2,wp_w3,wp_b3,w_temp,W);

  s1_mfma_kernel<<<dim3(8,128),256,0,stream>>>(qhi,qlo,khi,klo,rq1,rq2,mqp,qdmk,rk1,rk2,ks2,
                                               dsumH,marg,rcs,rcov);
  margfin_kernel<<<64,256,0,stream>>>(marg, dsumE);
  scalars1_kernel<<<1,1,0,stream>>>(dsumH, dsumE, W, coef);
  rowfold_kernel<<<256,256,0,stream>>>(marg, rcs, rcov, coef, dsumE);
  scalars2_kernel<<<1,1,0,stream>>>(dsumE, scal);

  s3_mfma_kernel<<<dim3(16,128),512,0,stream>>>(qhi,qlo,khi,klo,vth,vtl,
                                                rq1,mqp,qdmk,rk1,ks2,marg,coef,scal,outh,outl);
  final_gemm_kernel<<<dim3(16,32),256,0,stream>>>(outh, outl, woth, wotl, b_out, outf);
}